// Round 15
// baseline (697.488 us; speedup 1.0000x reference)
//
#include <hip/hip_runtime.h>
#include <stdint.h>

#define H_NODES 8191
#define NN 4096
#define DIMC 1024

typedef __bf16 bf16x8 __attribute__((ext_vector_type(8)));
typedef float f32x4 __attribute__((ext_vector_type(4)));

__device__ __forceinline__ float b2f(ushort u) {
  union { uint32_t i; float f; } x; x.i = ((uint32_t)u) << 16; return x.f;
}
__device__ __forceinline__ ushort f2b(float f) {
  union { float f; uint32_t i; } x; x.f = f;
  uint32_t r = x.i + 0x7FFFu + ((x.i >> 16) & 1u);
  return (ushort)(r >> 16);
}
__device__ __forceinline__ void load16f(const ushort* p, float* f) {
  const uint32_t* w = (const uint32_t*)p;
  #pragma unroll
  for (int i = 0; i < 8; ++i) {
    uint32_t v = w[i];
    f[2 * i]     = b2f((ushort)(v & 0xffff));
    f[2 * i + 1] = b2f((ushort)(v >> 16));
  }
}
__device__ __forceinline__ void store16b(ushort* p, const float* f) {
  uint32_t w[8];
  #pragma unroll
  for (int i = 0; i < 8; ++i)
    w[i] = (uint32_t)f2b(f[2 * i]) | ((uint32_t)f2b(f[2 * i + 1]) << 16);
  *(uint4*)p = *(const uint4*)&w[0];
  *(uint4*)(p + 8) = *(const uint4*)&w[4];
}

// ---------------- weight transpose + fp32->bf16 : dst[z][n][k] = bf16(W_z[k][n])
struct WPtrs { const float* w[8]; };

__global__ void __launch_bounds__(256) transpose_w_k(WPtrs wp, ushort* __restrict__ dst) {
  __shared__ float t[32][33];
  const float* src = wp.w[blockIdx.z];
  int c0 = blockIdx.x * 32, r0 = blockIdx.y * 32;
  int tx = threadIdx.x, ty = threadIdx.y;
  #pragma unroll
  for (int i = ty; i < 32; i += 8)
    t[i][tx] = src[(long)(r0 + i) * DIMC + c0 + tx];
  __syncthreads();
  ushort* d = dst + (long)blockIdx.z * DIMC * DIMC;
  #pragma unroll
  for (int i = ty; i < 32; i += 8)
    d[(long)(c0 + i) * DIMC + r0 + tx] = f2b(t[tx][i]);
}

// ---------------- x fp32 -> h leaf rows (bf16)
__global__ void __launch_bounds__(256) cvt_x_k(const float* __restrict__ x, ushort* __restrict__ h) {
  long t = (long)blockIdx.x * 256 + threadIdx.x;
  long i = t << 2;
  if (i >= (long)2 * NN * DIMC) return;
  long row = i >> 10;
  int col = (int)(i & 1023);
  long b = row >> 12;
  long n = row & 4095;
  float4 v = *(const float4*)(x + i);
  ushort* d = h + ((b * H_NODES + n) << 10) + col;
  uint2 pk;
  pk.x = (uint32_t)f2b(v.x) | ((uint32_t)f2b(v.y) << 16);
  pk.y = (uint32_t)f2b(v.z) | ((uint32_t)f2b(v.w) << 16);
  *(uint2*)d = pk;
}

// ---------------- pre = 0.5*(even+odd) — used ONCE for level 0
__global__ void __launch_bounds__(256) avg_pairs_k(const ushort* __restrict__ h,
    ushort* __restrict__ pre, int P, int offL) {
  long t = (long)blockIdx.x * 256 + threadIdx.x;
  if (t >= (long)2 * P * 128) return;
  int dblk = (int)(t & 127);
  long r = t >> 7;
  int b = (r >= P) ? 1 : 0;
  int p = (int)(r - (long)b * P);
  const ushort* c = h + (((long)(b * H_NODES + offL + 2 * p)) << 10) + dblk * 8;
  const uint4 a0 = *(const uint4*)c;
  const uint4 a1 = *(const uint4*)(c + DIMC);
  const uint32_t* pa = (const uint32_t*)&a0;
  const uint32_t* pb = (const uint32_t*)&a1;
  uint32_t outw[4];
  #pragma unroll
  for (int i = 0; i < 4; ++i) {
    float x0 = b2f((ushort)(pa[i] & 0xffff)), x1 = b2f((ushort)(pa[i] >> 16));
    float y0 = b2f((ushort)(pb[i] & 0xffff)), y1 = b2f((ushort)(pb[i] >> 16));
    ushort r0 = f2b(0.5f * (x0 + y0)), r1 = f2b(0.5f * (x1 + y1));
    outw[i] = (uint32_t)r0 | ((uint32_t)r1 << 16);
  }
  *(uint4*)(pre + (((long)(b * P + p)) << 10) + dblk * 8) = *(const uint4*)outw;
}

// ---------------- GEMM descriptor
struct GemmDesc {
  const ushort* A; long sAb;
  const ushort* Bt;
  const float* bias;
  void* C; long sCb; int ldc;
  int M; int outMode;     // 0 bf16, 1 bf16+bias, 2 fp32+bias
  int tX, tY;
  ushort* preC;           // optional: next-level pre output (avg of row pairs)
  long sPreB;             // batch stride of preC
};

// ---------------- 128x128 GEMM tile, BK=64: 2-buf (64 KiB), 1-ahead, 16 K-steps
// LDS tile 128 rows x 64 cols; 8 slots/row; slot = cb ^ (row&7) (free 2-way).
__device__ __forceinline__ void stage_tile(const GemmDesc& d, const ushort* Ab,
    int row0, int col0, ushort* lA, ushort* lB, int kt, int wave, int lane) {
  #pragma unroll
  for (int j = 0; j < 4; ++j) {
    int s = wave * 256 + j * 64 + lane;          // 0..1023
    int r = s >> 3, slot = s & 7;
    int gb = slot ^ (r & 7);                     // inverse swizzle on global source
    int gr = row0 + r; gr = (gr < d.M) ? gr : (d.M - 1);
    const ushort* srcA = Ab + (long)gr * DIMC + kt * 64 + gb * 8;
    __builtin_amdgcn_global_load_lds(
        (const __attribute__((address_space(1))) void*)(uintptr_t)srcA,
        (__attribute__((address_space(3))) void*)(uint32_t)(uintptr_t)(lA + s * 8),
        16, 0, 0);
    const ushort* srcB = d.Bt + (long)(col0 + r) * DIMC + kt * 64 + gb * 8;
    __builtin_amdgcn_global_load_lds(
        (const __attribute__((address_space(1))) void*)(uintptr_t)srcB,
        (__attribute__((address_space(3))) void*)(uint32_t)(uintptr_t)(lB + s * 8),
        16, 0, 0);
  }
}

__device__ __forceinline__ void gemm_tile(const GemmDesc& d, int bz, int row0, int col0,
    ushort (*lA)[8192], ushort (*lB)[8192], int tid) {
  const ushort* Ab = d.A + (long)bz * d.sAb;
  int wave = tid >> 6, lane = tid & 63;
  int wr = wave >> 1, wc = wave & 1;

  f32x4 acc[4][4];
  #pragma unroll
  for (int m = 0; m < 4; ++m)
    #pragma unroll
    for (int n = 0; n < 4; ++n) acc[m][n] = (f32x4){0.f, 0.f, 0.f, 0.f};

  stage_tile(d, Ab, row0, col0, lA[0], lB[0], 0, wave, lane);

  int rr = lane & 15, g4 = lane >> 4;
  for (int kt = 0; kt < 16; ++kt) {
    int cur = kt & 1;
    if (kt + 1 < 16) {
      stage_tile(d, Ab, row0, col0, lA[cur ^ 1], lB[cur ^ 1], kt + 1, wave, lane);
      asm volatile("s_waitcnt vmcnt(8)" ::: "memory");   // kt's 8 loads landed
    } else {
      asm volatile("s_waitcnt vmcnt(0)" ::: "memory");
    }
    __builtin_amdgcn_s_barrier();
    #pragma unroll
    for (int ks = 0; ks < 2; ++ks) {
      bf16x8 af[4], bfr[4];
      #pragma unroll
      for (int m = 0; m < 4; ++m) {
        int r = wr * 64 + m * 16 + rr;
        int slot = (ks * 4 + g4) ^ (r & 7);
        af[m] = *reinterpret_cast<const bf16x8*>(&lA[cur][r * 64 + slot * 8]);
      }
      #pragma unroll
      for (int n = 0; n < 4; ++n) {
        int r = wc * 64 + n * 16 + rr;
        int slot = (ks * 4 + g4) ^ (r & 7);
        bfr[n] = *reinterpret_cast<const bf16x8*>(&lB[cur][r * 64 + slot * 8]);
      }
      __builtin_amdgcn_s_setprio(1);
      #pragma unroll
      for (int m = 0; m < 4; ++m)
        #pragma unroll
        for (int n = 0; n < 4; ++n)
          acc[m][n] = __builtin_amdgcn_mfma_f32_16x16x32_bf16(af[m], bfr[n], acc[m][n], 0, 0, 0);
      __builtin_amdgcn_s_setprio(0);
    }
    __builtin_amdgcn_s_barrier();   // all reads done before next stage overwrites cur
  }

  int rq = lane >> 4;
  #pragma unroll
  for (int n = 0; n < 4; ++n) {
    int col = col0 + wc * 64 + n * 16 + rr;
    float bv = d.bias ? d.bias[col] : 0.0f;
    #pragma unroll
    for (int m = 0; m < 4; ++m) {
      int gr0 = row0 + wr * 64 + m * 16 + rq * 4;
      float vv[4];
      #pragma unroll
      for (int r = 0; r < 4; ++r) vv[r] = acc[m][n][r] + bv;
      #pragma unroll
      for (int r = 0; r < 4; ++r) {
        int gr = gr0 + r;
        if (gr < d.M) {
          long o = (long)bz * d.sCb + (long)gr * d.ldc + col;
          if (d.outMode == 2) ((float*)d.C)[o] = vv[r];
          else ((ushort*)d.C)[o] = f2b(vv[r]);
        }
      }
      if (d.preC) {   // fused next-level pre: avg of adjacent row pairs (thread-local)
        #pragma unroll
        for (int r = 0; r < 4; r += 2) {
          int gr = gr0 + r;
          if (gr + 1 < d.M)
            d.preC[(long)bz * d.sPreB + (long)(gr >> 1) * DIMC + col] =
                f2b(0.5f * (vv[r] + vv[r + 1]));
        }
      }
    }
  }
}

// ---------------- the ONE GEMM kernel: two descriptors per launch (proven codegen)
__global__ void __launch_bounds__(256) gemm_multi(GemmDesc d0, GemmDesc d1, int t0) {
  __shared__ __align__(16) ushort lA[2][8192];
  __shared__ __align__(16) ushort lB[2][8192];
  int t = blockIdx.x;
  const GemmDesc& d = (t < t0) ? d0 : d1;
  int u = (t < t0) ? t : t - t0;
  int per = d.tX * d.tY;
  int bz = u / per;
  int rem = u - bz * per;
  int ty = rem / d.tX;
  int tx = rem - ty * d.tX;
  gemm_tile(d, bz, tx * 128, ty * 128, lA, lB, threadIdx.x);
}

// ---------------- stage-1 merge: one wave per (b,p), all 16 heads, 16 elems/lane
__global__ void __launch_bounds__(256) merge_y2_k(const ushort* __restrict__ q,
    const ushort* __restrict__ kv, ushort* __restrict__ outp, int P) {
  int wave = threadIdx.x >> 6, lane = threadIdx.x & 63;
  long w = (long)blockIdx.x * 4 + wave;
  if (w >= (long)2 * P) return;
  int b = (w >= P) ? 1 : 0;
  int p = (int)(w - (long)b * P);
  const ushort* qp = q + (((long)(b * P + p)) << 10) + lane * 16;
  const ushort* kvb = kv + ((long)(b * 2 * P + 2 * p)) * 2048;
  float qf[16], k0f[16], k1f[16];
  load16f(qp, qf);
  load16f(kvb + lane * 16, k0f);
  load16f(kvb + 2048 + lane * 16, k1f);
  float d0 = 0.f, d1 = 0.f;
  #pragma unroll
  for (int j = 0; j < 16; ++j) { d0 += qf[j] * k0f[j]; d1 += qf[j] * k1f[j]; }
  d0 += __shfl_xor(d0, 1); d0 += __shfl_xor(d0, 2);
  d1 += __shfl_xor(d1, 1); d1 += __shfl_xor(d1, 2);
  float s0 = d0 * 0.125f, s1 = d1 * 0.125f;
  float mm = fmaxf(s0, s1);
  float e0 = expf(s0 - mm), e1 = expf(s1 - mm);
  float inv = 1.0f / (e0 + e1 + 1e-9f);
  float w0 = e0 * inv, w1 = e1 * inv;
  float v0f[16], v1f[16], ov[16];
  load16f(kvb + 1024 + lane * 16, v0f);
  load16f(kvb + 2048 + 1024 + lane * 16, v1f);
  #pragma unroll
  for (int j = 0; j < 16; ++j) ov[j] = w0 * v0f[j] + w1 * v1f[j];
  store16b(outp + (((long)(b * P + p)) << 10) + lane * 16, ov);
}

// ---------------- stage-2 gather attention: one wave per (b,n), all heads
__global__ void __launch_bounds__(256) attn_x2_k(const ushort* __restrict__ Q,
    const ushort* __restrict__ KV, ushort* __restrict__ outp) {
  int wave = threadIdx.x >> 6, lane = threadIdx.x & 63;
  long w = (long)blockIdx.x * 4 + wave;
  int n = (int)(w & 4095);
  int b = (int)(w >> 12);
  const ushort* KVb = KV + (long)b * H_NODES * 2048;
  float qf[16];
  load16f(Q + (((long)b * NN + n) << 10) + lane * 16, qf);
  int nb[13];
  nb[0] = n;
  #pragma unroll
  for (int l = 0; l < 12; ++l) nb[1 + l] = (8192 - (8192 >> l)) + ((n >> l) ^ 1);
  float s[13];
  #pragma unroll
  for (int i = 0; i < 13; ++i) {
    float kf[16];
    load16f(KVb + (long)nb[i] * 2048 + lane * 16, kf);
    float d = 0.f;
    #pragma unroll
    for (int j = 0; j < 16; ++j) d += qf[j] * kf[j];
    d += __shfl_xor(d, 1);
    d += __shfl_xor(d, 2);
    s[i] = d * 0.125f;
  }
  #pragma unroll
  for (int l = 0; l < 12; ++l)
    if (((n >> l) & 1) == 0) s[1 + l] = -__builtin_inff();
  float mm = s[0];
  #pragma unroll
  for (int i = 1; i < 13; ++i) mm = fmaxf(mm, s[i]);
  float e[13], sum = 0.f;
  #pragma unroll
  for (int i = 0; i < 13; ++i) { e[i] = expf(s[i] - mm); sum += e[i]; }
  float inv = 1.0f / sum;
  float ov[16];
  #pragma unroll
  for (int j = 0; j < 16; ++j) ov[j] = 0.f;
  #pragma unroll
  for (int i = 0; i < 13; ++i) {
    float wgt = e[i] * inv;
    float vf[16];
    load16f(KVb + (long)nb[i] * 2048 + 1024 + lane * 16, vf);
    #pragma unroll
    for (int j = 0; j < 16; ++j) ov[j] += wgt * vf[j];
  }
  store16b(outp + (((long)b * NN + n) << 10) + lane * 16, ov);
}

extern "C" void kernel_launch(void* const* d_in, const int* in_sizes, int n_in,
                              void* d_out, int out_size, void* d_ws, size_t ws_size,
                              hipStream_t stream) {
  const float* x    = (const float*)d_in[0];
  const float* Wq_y = (const float*)d_in[1];
  const float* Wk_y = (const float*)d_in[2];
  const float* Wv_y = (const float*)d_in[3];
  const float* Wo_y = (const float*)d_in[4];
  const float* bo_y = (const float*)d_in[5];
  const float* Wq_x = (const float*)d_in[6];
  const float* Wk_x = (const float*)d_in[7];
  const float* Wv_x = (const float*)d_in[8];
  const float* Wo_x = (const float*)d_in[9];
  const float* bo_x = (const float*)d_in[10];

  ushort* wt  = (ushort*)d_ws;                              // 8 x 1M bf16 weights^T
  ushort* h   = wt + (size_t)8 * 1024 * 1024;               // [B][8191][1024]
  ushort* reg = h + (size_t)2 * H_NODES * DIMC;
  // stage-2 layout (attached writes begin at level-0 O launch)
  ushort* Qx   = reg;                                       // [B][4096][1024]
  ushort* KVa  = Qx + (size_t)2 * 4096 * DIMC;              // [B][8191][2048]
  ushort* aout = KVa + (size_t)2 * H_NODES * 2048;          // [B][4096][1024]
  // stage-1 scratch lives after aout (aout itself only written by attn, last)
  ushort* preB = aout;                                      // [B][2048][1024]
  ushort* qbB  = preB + (size_t)2 * 2048 * DIMC;            // [B][2048][1024]
  ushort* kv1B = qbB + (size_t)2 * 2048 * DIMC;             // [B][4096][2048]
  ushort* mrgB = kv1B + (size_t)2 * 4096 * 2048;            // [B][2048][1024]
  ushort* preS = preB;
  ushort* qbS  = qbB;
  ushort* kv1S = kv1B;
  ushort* mrgS = mrgB;

  size_t wsElems = (size_t)8 * 1024 * 1024 + (size_t)2 * H_NODES * DIMC +
                   (size_t)2 * 4096 * DIMC + (size_t)2 * H_NODES * 2048 +
                   ((size_t)2 * 2048 * DIMC * 2 + (size_t)2 * 4096 * 2048 +
                    (size_t)2 * 2048 * DIMC);
  if (ws_size < wsElems * 2) return;

  WPtrs wp;
  wp.w[0] = Wq_y; wp.w[1] = Wk_y; wp.w[2] = Wv_y; wp.w[3] = Wo_y;
  wp.w[4] = Wq_x; wp.w[5] = Wk_x; wp.w[6] = Wv_x; wp.w[7] = Wo_x;
  transpose_w_k<<<dim3(32, 32, 8), dim3(32, 8), 0, stream>>>(wp, wt);
  cvt_x_k<<<8192, 256, 0, stream>>>(x, h);
  avg_pairs_k<<<(2 * 2048 * 128 + 255) / 256, 256, 0, stream>>>(h, preB, 2048, 0);

  auto mk128 = [](const ushort* A, long sAb, const ushort* Bt, const float* bias,
                  void* C, long sCb, int ldc, int M, int outMode, int tY) {
    GemmDesc d; d.A = A; d.sAb = sAb; d.Bt = Bt; d.bias = bias; d.C = C; d.sCb = sCb;
    d.ldc = ldc; d.M = M; d.outMode = outMode; d.tX = (M + 127) / 128; d.tY = tY;
    d.preC = nullptr; d.sPreB = 0;
    return d;
  };
  auto kvSub = [&](long start, int len) {
    return mk128(h + start * DIMC, (long)H_NODES * DIMC, wt + (size_t)5 * 1024 * 1024,
                 nullptr, KVa + start * 2048, (long)H_NODES * 2048, 2048, len, 0, 16);
  };
  auto qSub = [&](long start, int len) {
    return mk128(h + start * DIMC, (long)H_NODES * DIMC, wt + (size_t)4 * 1024 * 1024,
                 nullptr, Qx + start * DIMC, (long)4096 * DIMC, DIMC, len, 0, 8);
  };

  for (int l = 0; l < 12; ++l) {
    int P = NN >> (l + 1);
    int offL = 8192 - (8192 >> l);
    int offP = 8192 - (8192 >> (l + 1));
    ushort* pre = (l >= 3) ? preS : preB;
    ushort* qb  = (l >= 3) ? qbS  : qbB;
    ushort* kv1 = (l >= 3) ? kv1S : kv1B;
    ushort* mrg = (l >= 3) ? mrgS : mrgB;

    GemmDesc dq  = mk128(pre, (long)P * DIMC, wt, nullptr,
                         qb, (long)P * DIMC, DIMC, P, 0, 8);
    GemmDesc dkv = mk128(h + (long)offL * DIMC, (long)H_NODES * DIMC,
                         wt + (size_t)1 * 1024 * 1024, nullptr,
                         kv1, (long)2 * P * 2048, 2048, 2 * P, 0, 16);
    int t0 = dq.tX * dq.tY * 2;
    gemm_multi<<<t0 + dkv.tX * dkv.tY * 2, 256, 0, stream>>>(dq, dkv, t0);

    merge_y2_k<<<(2 * P + 3) / 4, 256, 0, stream>>>(qb, kv1, mrg, P);

    GemmDesc dgo = mk128(mrg, (long)P * DIMC, wt + (size_t)3 * 1024 * 1024, bo_y,
                         h + (long)offP * DIMC, (long)H_NODES * DIMC, DIMC, P, 1, 8);
    if (l < 11) {                       // fused pre for next level
      dgo.preC = (l >= 2) ? preS : preB;
      dgo.sPreB = (long)(P / 2) * DIMC;
    }
    // attach schedule (availability: rows < 8192 - (2048>>(l-1)))
    GemmDesc att = dgo; int nAtt = 0;
    if      (l == 0)  att = qSub(0, 2048);
    else if (l == 1)  att = qSub(2048, 2048);
    else if (l == 2)  att = kvSub(0, 1792);
    else if (l == 3)  att = kvSub(1792, 1920);
    else if (l == 4)  att = kvSub(3712, 1920);
    else if (l == 5)  att = kvSub(5632, 1536);
    else if (l == 6)  att = kvSub(7168, 512);
    else if (l == 7)  att = kvSub(7680, 256);
    else if (l == 8)  att = kvSub(7936, 128);
    else if (l == 9)  att = kvSub(8064, 64);
    else if (l == 10) att = kvSub(8128, 32);
    else if (l == 11) att = kvSub(8160, 16);
    nAtt = att.tX * att.tY * 2;
    int n0 = dgo.tX * dgo.tY * 2;
    gemm_multi<<<n0 + nAtt, 256, 0, stream>>>(dgo, att, n0);
  }

  // leftover KV dribble (rows 8176..8190, incl. root; available after l11 O)
  {
    GemmDesc a0 = kvSub(8176, 8), a1 = kvSub(8184, 7);
    int n0 = a0.tX * a0.tY * 2, n1 = a1.tX * a1.tY * 2;
    gemm_multi<<<n0 + n1, 256, 0, stream>>>(a0, a1, n0);
  }
  attn_x2_k<<<2048, 256, 0, stream>>>(Qx, KVa, aout);
  {
    GemmDesc dox = mk128(aout, (long)4096 * DIMC, wt + (size_t)7 * 1024 * 1024, bo_x,
                         d_out, (long)4096 * DIMC, DIMC, 4096, 2, 8);
    gemm_multi<<<dox.tX * dox.tY * 2, 256, 0, stream>>>(dox, dox, dox.tX * dox.tY * 2);
  }
}

// Round 16
// 671.419 us; speedup vs baseline: 1.0388x; 1.0388x over previous
//
#include <hip/hip_runtime.h>
#include <stdint.h>

#define H_NODES 8191
#define NN 4096
#define DIMC 1024

typedef __bf16 bf16x8 __attribute__((ext_vector_type(8)));
typedef float f32x4 __attribute__((ext_vector_type(4)));

__device__ __forceinline__ float b2f(ushort u) {
  union { uint32_t i; float f; } x; x.i = ((uint32_t)u) << 16; return x.f;
}
__device__ __forceinline__ ushort f2b(float f) {
  union { float f; uint32_t i; } x; x.f = f;
  uint32_t r = x.i + 0x7FFFu + ((x.i >> 16) & 1u);
  return (ushort)(r >> 16);
}
__device__ __forceinline__ void load16f(const ushort* p, float* f) {
  const uint32_t* w = (const uint32_t*)p;
  #pragma unroll
  for (int i = 0; i < 8; ++i) {
    uint32_t v = w[i];
    f[2 * i]     = b2f((ushort)(v & 0xffff));
    f[2 * i + 1] = b2f((ushort)(v >> 16));
  }
}
__device__ __forceinline__ void store16b(ushort* p, const float* f) {
  uint32_t w[8];
  #pragma unroll
  for (int i = 0; i < 8; ++i)
    w[i] = (uint32_t)f2b(f[2 * i]) | ((uint32_t)f2b(f[2 * i + 1]) << 16);
  *(uint4*)p = *(const uint4*)&w[0];
  *(uint4*)(p + 8) = *(const uint4*)&w[4];
}

// ---------------- weight transpose + fp32->bf16 : dst[z][n][k] = bf16(W_z[k][n])
struct WPtrs { const float* w[8]; };

__global__ void __launch_bounds__(256) transpose_w_k(WPtrs wp, ushort* __restrict__ dst) {
  __shared__ float t[32][33];
  const float* src = wp.w[blockIdx.z];
  int c0 = blockIdx.x * 32, r0 = blockIdx.y * 32;
  int tx = threadIdx.x, ty = threadIdx.y;
  #pragma unroll
  for (int i = ty; i < 32; i += 8)
    t[i][tx] = src[(long)(r0 + i) * DIMC + c0 + tx];
  __syncthreads();
  ushort* d = dst + (long)blockIdx.z * DIMC * DIMC;
  #pragma unroll
  for (int i = ty; i < 32; i += 8)
    d[(long)(c0 + i) * DIMC + r0 + tx] = f2b(t[tx][i]);
}

// ---------------- x fp32 -> h leaf rows (bf16)
__global__ void __launch_bounds__(256) cvt_x_k(const float* __restrict__ x, ushort* __restrict__ h) {
  long t = (long)blockIdx.x * 256 + threadIdx.x;
  long i = t << 2;
  if (i >= (long)2 * NN * DIMC) return;
  long row = i >> 10;
  int col = (int)(i & 1023);
  long b = row >> 12;
  long n = row & 4095;
  float4 v = *(const float4*)(x + i);
  ushort* d = h + ((b * H_NODES + n) << 10) + col;
  uint2 pk;
  pk.x = (uint32_t)f2b(v.x) | ((uint32_t)f2b(v.y) << 16);
  pk.y = (uint32_t)f2b(v.z) | ((uint32_t)f2b(v.w) << 16);
  *(uint2*)d = pk;
}

// ---------------- pre = 0.5*(even+odd) — used ONCE for level 0
__global__ void __launch_bounds__(256) avg_pairs_k(const ushort* __restrict__ h,
    ushort* __restrict__ pre, int P, int offL) {
  long t = (long)blockIdx.x * 256 + threadIdx.x;
  if (t >= (long)2 * P * 128) return;
  int dblk = (int)(t & 127);
  long r = t >> 7;
  int b = (r >= P) ? 1 : 0;
  int p = (int)(r - (long)b * P);
  const ushort* c = h + (((long)(b * H_NODES + offL + 2 * p)) << 10) + dblk * 8;
  const uint4 a0 = *(const uint4*)c;
  const uint4 a1 = *(const uint4*)(c + DIMC);
  const uint32_t* pa = (const uint32_t*)&a0;
  const uint32_t* pb = (const uint32_t*)&a1;
  uint32_t outw[4];
  #pragma unroll
  for (int i = 0; i < 4; ++i) {
    float x0 = b2f((ushort)(pa[i] & 0xffff)), x1 = b2f((ushort)(pa[i] >> 16));
    float y0 = b2f((ushort)(pb[i] & 0xffff)), y1 = b2f((ushort)(pb[i] >> 16));
    ushort r0 = f2b(0.5f * (x0 + y0)), r1 = f2b(0.5f * (x1 + y1));
    outw[i] = (uint32_t)r0 | ((uint32_t)r1 << 16);
  }
  *(uint4*)(pre + (((long)(b * P + p)) << 10) + dblk * 8) = *(const uint4*)outw;
}

// ---------------- GEMM descriptor
struct GemmDesc {
  const ushort* A; long sAb;
  const ushort* Bt;
  const float* bias;
  void* C; long sCb; int ldc;
  int M; int outMode;     // 0 bf16, 1 bf16+bias, 2 fp32+bias
  int tX, tY;
  ushort* preC;           // optional: next-level pre output (avg of row pairs)
  long sPreB;             // batch stride of preC
};

// ---------------- 128x128 GEMM tile, split-K x2: 8 waves, 2 K-groups of 16 steps
// smem layout (64 KiB): A[grp][buf] at (grp*2+buf)*4096, B at 16384 + same.
__device__ __forceinline__ void stage_tile(const GemmDesc& d, const ushort* Ab,
    int row0, int col0, ushort* lA, ushort* lB, int ktG, int wg, int lane) {
  #pragma unroll
  for (int j = 0; j < 2; ++j) {
    int s = wg * 128 + j * 64 + lane;          // 0..511
    int r = s >> 2;
    int g = (s & 3) ^ ((r >> 1) & 3);          // pre-swizzled source k-block
    int gr = row0 + r; gr = (gr < d.M) ? gr : (d.M - 1);
    const ushort* srcA = Ab + (long)gr * DIMC + ktG * 32 + g * 8;
    __builtin_amdgcn_global_load_lds(
        (const __attribute__((address_space(1))) void*)(uintptr_t)srcA,
        (__attribute__((address_space(3))) void*)(uint32_t)(uintptr_t)(lA + s * 8),
        16, 0, 0);
    const ushort* srcB = d.Bt + (long)(col0 + r) * DIMC + ktG * 32 + g * 8;
    __builtin_amdgcn_global_load_lds(
        (const __attribute__((address_space(1))) void*)(uintptr_t)srcB,
        (__attribute__((address_space(3))) void*)(uint32_t)(uintptr_t)(lB + s * 8),
        16, 0, 0);
  }
}

__device__ __forceinline__ void gemm_tile(const GemmDesc& d, int bz, int row0, int col0,
    ushort* smem, int tid) {
  const ushort* Ab = d.A + (long)bz * d.sAb;
  int wave = tid >> 6, lane = tid & 63;
  int grp = wave >> 2, wg = wave & 3;
  int wr = wg >> 1, wc = wg & 1;
  ushort* aB0 = smem + (grp * 2) * 4096;
  ushort* aB1 = smem + (grp * 2 + 1) * 4096;
  ushort* bB0 = smem + 16384 + (grp * 2) * 4096;
  ushort* bB1 = smem + 16384 + (grp * 2 + 1) * 4096;

  f32x4 acc[4][4];
  #pragma unroll
  for (int m = 0; m < 4; ++m)
    #pragma unroll
    for (int n = 0; n < 4; ++n) acc[m][n] = (f32x4){0.f, 0.f, 0.f, 0.f};

  stage_tile(d, Ab, row0, col0, aB0, bB0, grp * 16, wg, lane);

  int rr = lane & 15, g4 = lane >> 4;
  for (int kt = 0; kt < 16; ++kt) {
    ushort* aCur = (kt & 1) ? aB1 : aB0;
    ushort* bCur = (kt & 1) ? bB1 : bB0;
    if (kt + 1 < 16) {
      ushort* aNxt = (kt & 1) ? aB0 : aB1;
      ushort* bNxt = (kt & 1) ? bB0 : bB1;
      stage_tile(d, Ab, row0, col0, aNxt, bNxt, grp * 16 + kt + 1, wg, lane);
      asm volatile("s_waitcnt vmcnt(4)" ::: "memory");   // kt's loads landed
    } else {
      asm volatile("s_waitcnt vmcnt(0)" ::: "memory");
    }
    __builtin_amdgcn_s_barrier();
    bf16x8 af[4], bfr[4];
    #pragma unroll
    for (int m = 0; m < 4; ++m) {
      int r = wr * 64 + m * 16 + rr;
      int slot = g4 ^ ((r >> 1) & 3);
      af[m] = *reinterpret_cast<const bf16x8*>(&aCur[r * 32 + slot * 8]);
    }
    #pragma unroll
    for (int n = 0; n < 4; ++n) {
      int r = wc * 64 + n * 16 + rr;
      int slot = g4 ^ ((r >> 1) & 3);
      bfr[n] = *reinterpret_cast<const bf16x8*>(&bCur[r * 32 + slot * 8]);
    }
    __builtin_amdgcn_s_setprio(1);
    #pragma unroll
    for (int m = 0; m < 4; ++m)
      #pragma unroll
      for (int n = 0; n < 4; ++n)
        acc[m][n] = __builtin_amdgcn_mfma_f32_16x16x32_bf16(af[m], bfr[n], acc[m][n], 0, 0, 0);
    __builtin_amdgcn_s_setprio(0);
    __builtin_amdgcn_s_barrier();   // reads done before next stage overwrites cur
  }

  // cross-group reduce: group1 acc -> LDS (f32x4 SoA, conflict-free) -> group0 adds
  __builtin_amdgcn_s_barrier();
  f32x4* red = (f32x4*)smem;        // 16 x 256 x 16B = 64 KiB (full smem reuse)
  if (grp == 1) {
    int q = tid - 256;
    #pragma unroll
    for (int m = 0; m < 4; ++m)
      #pragma unroll
      for (int n = 0; n < 4; ++n)
        red[(m * 4 + n) * 256 + q] = acc[m][n];
  }
  __builtin_amdgcn_s_barrier();
  asm volatile("s_waitcnt lgkmcnt(0)" ::: "memory");
  if (grp != 0) return;

  #pragma unroll
  for (int m = 0; m < 4; ++m)
    #pragma unroll
    for (int n = 0; n < 4; ++n)
      acc[m][n] += red[(m * 4 + n) * 256 + tid];

  int rq = lane >> 4;
  #pragma unroll
  for (int n = 0; n < 4; ++n) {
    int col = col0 + wc * 64 + n * 16 + rr;
    float bv = d.bias ? d.bias[col] : 0.0f;
    #pragma unroll
    for (int m = 0; m < 4; ++m) {
      int gr0 = row0 + wr * 64 + m * 16 + rq * 4;
      float vv[4];
      #pragma unroll
      for (int r = 0; r < 4; ++r) vv[r] = acc[m][n][r] + bv;
      #pragma unroll
      for (int r = 0; r < 4; ++r) {
        int gr = gr0 + r;
        if (gr < d.M) {
          long o = (long)bz * d.sCb + (long)gr * d.ldc + col;
          if (d.outMode == 2) ((float*)d.C)[o] = vv[r];
          else ((ushort*)d.C)[o] = f2b(vv[r]);
        }
      }
      if (d.preC) {   // fused next-level pre: avg of adjacent row pairs (thread-local)
        #pragma unroll
        for (int r = 0; r < 4; r += 2) {
          int gr = gr0 + r;
          if (gr + 1 < d.M)
            d.preC[(long)bz * d.sPreB + (long)(gr >> 1) * DIMC + col] =
                f2b(0.5f * (vv[r] + vv[r + 1]));
        }
      }
    }
  }
}

// ---------------- the ONE GEMM kernel: two descriptors per launch (proven codegen)
__global__ void __launch_bounds__(512) gemm_multi(GemmDesc d0, GemmDesc d1, int t0) {
  __shared__ __align__(16) ushort smem[32768];   // 64 KiB
  int t = blockIdx.x;
  const GemmDesc& d = (t < t0) ? d0 : d1;
  int u = (t < t0) ? t : t - t0;
  int per = d.tX * d.tY;
  int bz = u / per;
  int rem = u - bz * per;
  int ty = rem / d.tX;
  int tx = rem - ty * d.tX;
  gemm_tile(d, bz, tx * 128, ty * 128, smem, threadIdx.x);
}

// ---------------- stage-1 merge: one wave per (b,p), all 16 heads, 16 elems/lane
__global__ void __launch_bounds__(256) merge_y2_k(const ushort* __restrict__ q,
    const ushort* __restrict__ kv, ushort* __restrict__ outp, int P) {
  int wave = threadIdx.x >> 6, lane = threadIdx.x & 63;
  long w = (long)blockIdx.x * 4 + wave;
  if (w >= (long)2 * P) return;
  int b = (w >= P) ? 1 : 0;
  int p = (int)(w - (long)b * P);
  const ushort* qp = q + (((long)(b * P + p)) << 10) + lane * 16;
  const ushort* kvb = kv + ((long)(b * 2 * P + 2 * p)) * 2048;
  float qf[16], k0f[16], k1f[16];
  load16f(qp, qf);
  load16f(kvb + lane * 16, k0f);
  load16f(kvb + 2048 + lane * 16, k1f);
  float d0 = 0.f, d1 = 0.f;
  #pragma unroll
  for (int j = 0; j < 16; ++j) { d0 += qf[j] * k0f[j]; d1 += qf[j] * k1f[j]; }
  d0 += __shfl_xor(d0, 1); d0 += __shfl_xor(d0, 2);
  d1 += __shfl_xor(d1, 1); d1 += __shfl_xor(d1, 2);
  float s0 = d0 * 0.125f, s1 = d1 * 0.125f;
  float mm = fmaxf(s0, s1);
  float e0 = expf(s0 - mm), e1 = expf(s1 - mm);
  float inv = 1.0f / (e0 + e1 + 1e-9f);
  float w0 = e0 * inv, w1 = e1 * inv;
  float v0f[16], v1f[16], ov[16];
  load16f(kvb + 1024 + lane * 16, v0f);
  load16f(kvb + 2048 + 1024 + lane * 16, v1f);
  #pragma unroll
  for (int j = 0; j < 16; ++j) ov[j] = w0 * v0f[j] + w1 * v1f[j];
  store16b(outp + (((long)(b * P + p)) << 10) + lane * 16, ov);
}

// ---------------- stage-2 gather attention: one wave per (b,n), all heads
__global__ void __launch_bounds__(256) attn_x2_k(const ushort* __restrict__ Q,
    const ushort* __restrict__ KV, ushort* __restrict__ outp) {
  int wave = threadIdx.x >> 6, lane = threadIdx.x & 63;
  long w = (long)blockIdx.x * 4 + wave;
  int n = (int)(w & 4095);
  int b = (int)(w >> 12);
  const ushort* KVb = KV + (long)b * H_NODES * 2048;
  float qf[16];
  load16f(Q + (((long)b * NN + n) << 10) + lane * 16, qf);
  int nb[13];
  nb[0] = n;
  #pragma unroll
  for (int l = 0; l < 12; ++l) nb[1 + l] = (8192 - (8192 >> l)) + ((n >> l) ^ 1);
  float s[13];
  #pragma unroll
  for (int i = 0; i < 13; ++i) {
    float kf[16];
    load16f(KVb + (long)nb[i] * 2048 + lane * 16, kf);
    float d = 0.f;
    #pragma unroll
    for (int j = 0; j < 16; ++j) d += qf[j] * kf[j];
    d += __shfl_xor(d, 1);
    d += __shfl_xor(d, 2);
    s[i] = d * 0.125f;
  }
  #pragma unroll
  for (int l = 0; l < 12; ++l)
    if (((n >> l) & 1) == 0) s[1 + l] = -__builtin_inff();
  float mm = s[0];
  #pragma unroll
  for (int i = 1; i < 13; ++i) mm = fmaxf(mm, s[i]);
  float e[13], sum = 0.f;
  #pragma unroll
  for (int i = 0; i < 13; ++i) { e[i] = expf(s[i] - mm); sum += e[i]; }
  float inv = 1.0f / sum;
  float ov[16];
  #pragma unroll
  for (int j = 0; j < 16; ++j) ov[j] = 0.f;
  #pragma unroll
  for (int i = 0; i < 13; ++i) {
    float wgt = e[i] * inv;
    float vf[16];
    load16f(KVb + (long)nb[i] * 2048 + 1024 + lane * 16, vf);
    #pragma unroll
    for (int j = 0; j < 16; ++j) ov[j] += wgt * vf[j];
  }
  store16b(outp + (((long)b * NN + n) << 10) + lane * 16, ov);
}

extern "C" void kernel_launch(void* const* d_in, const int* in_sizes, int n_in,
                              void* d_out, int out_size, void* d_ws, size_t ws_size,
                              hipStream_t stream) {
  const float* x    = (const float*)d_in[0];
  const float* Wq_y = (const float*)d_in[1];
  const float* Wk_y = (const float*)d_in[2];
  const float* Wv_y = (const float*)d_in[3];
  const float* Wo_y = (const float*)d_in[4];
  const float* bo_y = (const float*)d_in[5];
  const float* Wq_x = (const float*)d_in[6];
  const float* Wk_x = (const float*)d_in[7];
  const float* Wv_x = (const float*)d_in[8];
  const float* Wo_x = (const float*)d_in[9];
  const float* bo_x = (const float*)d_in[10];

  ushort* wt  = (ushort*)d_ws;                              // 8 x 1M bf16 weights^T
  ushort* h   = wt + (size_t)8 * 1024 * 1024;               // [B][8191][1024]
  ushort* reg = h + (size_t)2 * H_NODES * DIMC;
  ushort* Qx   = reg;                                       // [B][4096][1024]
  ushort* KVa  = Qx + (size_t)2 * 4096 * DIMC;              // [B][8191][2048]
  ushort* aout = KVa + (size_t)2 * H_NODES * 2048;          // [B][4096][1024]
  ushort* preB = aout;                                      // [B][2048][1024]
  ushort* qbB  = preB + (size_t)2 * 2048 * DIMC;            // [B][2048][1024]
  ushort* kv1B = qbB + (size_t)2 * 2048 * DIMC;             // [B][4096][2048]
  ushort* mrgB = kv1B + (size_t)2 * 4096 * 2048;            // [B][2048][1024]
  ushort* preS = preB;
  ushort* qbS  = qbB;
  ushort* kv1S = kv1B;
  ushort* mrgS = mrgB;

  size_t wsElems = (size_t)8 * 1024 * 1024 + (size_t)2 * H_NODES * DIMC +
                   (size_t)2 * 4096 * DIMC + (size_t)2 * H_NODES * 2048 +
                   ((size_t)2 * 2048 * DIMC * 2 + (size_t)2 * 4096 * 2048 +
                    (size_t)2 * 2048 * DIMC);
  if (ws_size < wsElems * 2) return;

  WPtrs wp;
  wp.w[0] = Wq_y; wp.w[1] = Wk_y; wp.w[2] = Wv_y; wp.w[3] = Wo_y;
  wp.w[4] = Wq_x; wp.w[5] = Wk_x; wp.w[6] = Wv_x; wp.w[7] = Wo_x;
  transpose_w_k<<<dim3(32, 32, 8), dim3(32, 8), 0, stream>>>(wp, wt);
  cvt_x_k<<<8192, 256, 0, stream>>>(x, h);
  avg_pairs_k<<<(2 * 2048 * 128 + 255) / 256, 256, 0, stream>>>(h, preB, 2048, 0);

  auto mk128 = [](const ushort* A, long sAb, const ushort* Bt, const float* bias,
                  void* C, long sCb, int ldc, int M, int outMode, int tY) {
    GemmDesc d; d.A = A; d.sAb = sAb; d.Bt = Bt; d.bias = bias; d.C = C; d.sCb = sCb;
    d.ldc = ldc; d.M = M; d.outMode = outMode; d.tX = (M + 127) / 128; d.tY = tY;
    d.preC = nullptr; d.sPreB = 0;
    return d;
  };
  auto kvSub = [&](long start, int len) {
    return mk128(h + start * DIMC, (long)H_NODES * DIMC, wt + (size_t)5 * 1024 * 1024,
                 nullptr, KVa + start * 2048, (long)H_NODES * 2048, 2048, len, 0, 16);
  };
  auto qSub = [&](long start, int len) {
    return mk128(h + start * DIMC, (long)H_NODES * DIMC, wt + (size_t)4 * 1024 * 1024,
                 nullptr, Qx + start * DIMC, (long)4096 * DIMC, DIMC, len, 0, 8);
  };

  for (int l = 0; l < 12; ++l) {
    int P = NN >> (l + 1);
    int offL = 8192 - (8192 >> l);
    int offP = 8192 - (8192 >> (l + 1));
    ushort* pre = (l >= 3) ? preS : preB;
    ushort* qb  = (l >= 3) ? qbS  : qbB;
    ushort* kv1 = (l >= 3) ? kv1S : kv1B;
    ushort* mrg = (l >= 3) ? mrgS : mrgB;

    GemmDesc dq  = mk128(pre, (long)P * DIMC, wt, nullptr,
                         qb, (long)P * DIMC, DIMC, P, 0, 8);
    GemmDesc dkv = mk128(h + (long)offL * DIMC, (long)H_NODES * DIMC,
                         wt + (size_t)1 * 1024 * 1024, nullptr,
                         kv1, (long)2 * P * 2048, 2048, 2 * P, 0, 16);
    int t0 = dq.tX * dq.tY * 2;
    gemm_multi<<<t0 + dkv.tX * dkv.tY * 2, 512, 0, stream>>>(dq, dkv, t0);

    merge_y2_k<<<(2 * P + 3) / 4, 256, 0, stream>>>(qb, kv1, mrg, P);

    GemmDesc dgo = mk128(mrg, (long)P * DIMC, wt + (size_t)3 * 1024 * 1024, bo_y,
                         h + (long)offP * DIMC, (long)H_NODES * DIMC, DIMC, P, 1, 8);
    if (l < 11) {                       // fused pre for next level
      dgo.preC = (l >= 2) ? preS : preB;
      dgo.sPreB = (long)(P / 2) * DIMC;
    }
    // attach schedule (availability: rows < 8192 - (2048>>(l-1)))
    GemmDesc att = dgo; int nAtt = 0;
    if      (l == 0)  att = qSub(0, 2048);
    else if (l == 1)  att = qSub(2048, 2048);
    else if (l == 2)  att = kvSub(0, 1792);
    else if (l == 3)  att = kvSub(1792, 1920);
    else if (l == 4)  att = kvSub(3712, 1920);
    else if (l == 5)  att = kvSub(5632, 1536);
    else if (l == 6)  att = kvSub(7168, 512);
    else if (l == 7)  att = kvSub(7680, 256);
    else if (l == 8)  att = kvSub(7936, 128);
    else if (l == 9)  att = kvSub(8064, 64);
    else if (l == 10) att = kvSub(8128, 32);
    else if (l == 11) att = kvSub(8160, 16);
    nAtt = att.tX * att.tY * 2;
    int n0 = dgo.tX * dgo.tY * 2;
    gemm_multi<<<n0 + nAtt, 512, 0, stream>>>(dgo, att, n0);
  }

  // leftover KV dribble (rows 8176..8190, incl. root; available after l11 O)
  {
    GemmDesc a0 = kvSub(8176, 8), a1 = kvSub(8184, 7);
    int n0 = a0.tX * a0.tY * 2, n1 = a1.tX * a1.tY * 2;
    gemm_multi<<<n0 + n1, 512, 0, stream>>>(a0, a1, n0);
  }
  attn_x2_k<<<2048, 256, 0, stream>>>(Qx, KVa, aout);
  {
    GemmDesc dox = mk128(aout, (long)4096 * DIMC, wt + (size_t)7 * 1024 * 1024, bo_x,
                         d_out, (long)4096 * DIMC, DIMC, 4096, 2, 8);
    gemm_multi<<<dox.tX * dox.tY * 2, 512, 0, stream>>>(dox, dox, dox.tX * dox.tY * 2);
  }
}

// Round 17
// 644.830 us; speedup vs baseline: 1.0817x; 1.0412x over previous
//
#include <hip/hip_runtime.h>
#include <stdint.h>

#define H_NODES 8191
#define NN 4096
#define DIMC 1024

typedef __bf16 bf16x8 __attribute__((ext_vector_type(8)));
typedef float f32x4 __attribute__((ext_vector_type(4)));

__device__ __forceinline__ float b2f(ushort u) {
  union { uint32_t i; float f; } x; x.i = ((uint32_t)u) << 16; return x.f;
}
__device__ __forceinline__ ushort f2b(float f) {
  union { float f; uint32_t i; } x; x.f = f;
  uint32_t r = x.i + 0x7FFFu + ((x.i >> 16) & 1u);
  return (ushort)(r >> 16);
}
__device__ __forceinline__ void load16f(const ushort* p, float* f) {
  const uint32_t* w = (const uint32_t*)p;
  #pragma unroll
  for (int i = 0; i < 8; ++i) {
    uint32_t v = w[i];
    f[2 * i]     = b2f((ushort)(v & 0xffff));
    f[2 * i + 1] = b2f((ushort)(v >> 16));
  }
}
__device__ __forceinline__ void store16b(ushort* p, const float* f) {
  uint32_t w[8];
  #pragma unroll
  for (int i = 0; i < 8; ++i)
    w[i] = (uint32_t)f2b(f[2 * i]) | ((uint32_t)f2b(f[2 * i + 1]) << 16);
  *(uint4*)p = *(const uint4*)&w[0];
  *(uint4*)(p + 8) = *(const uint4*)&w[4];
}

// ---------------- weight transpose + fp32->bf16 : dst[z][n][k] = bf16(W_z[k][n])
struct WPtrs { const float* w[8]; };

__global__ void __launch_bounds__(256) transpose_w_k(WPtrs wp, ushort* __restrict__ dst) {
  __shared__ float t[32][33];
  const float* src = wp.w[blockIdx.z];
  int c0 = blockIdx.x * 32, r0 = blockIdx.y * 32;
  int tx = threadIdx.x, ty = threadIdx.y;
  #pragma unroll
  for (int i = ty; i < 32; i += 8)
    t[i][tx] = src[(long)(r0 + i) * DIMC + c0 + tx];
  __syncthreads();
  ushort* d = dst + (long)blockIdx.z * DIMC * DIMC;
  #pragma unroll
  for (int i = ty; i < 32; i += 8)
    d[(long)(c0 + i) * DIMC + r0 + tx] = f2b(t[tx][i]);
}

// ---------------- x fp32 -> h leaf rows (bf16)
__global__ void __launch_bounds__(256) cvt_x_k(const float* __restrict__ x, ushort* __restrict__ h) {
  long t = (long)blockIdx.x * 256 + threadIdx.x;
  long i = t << 2;
  if (i >= (long)2 * NN * DIMC) return;
  long row = i >> 10;
  int col = (int)(i & 1023);
  long b = row >> 12;
  long n = row & 4095;
  float4 v = *(const float4*)(x + i);
  ushort* d = h + ((b * H_NODES + n) << 10) + col;
  uint2 pk;
  pk.x = (uint32_t)f2b(v.x) | ((uint32_t)f2b(v.y) << 16);
  pk.y = (uint32_t)f2b(v.z) | ((uint32_t)f2b(v.w) << 16);
  *(uint2*)d = pk;
}

// ---------------- pre = 0.5*(even+odd) — used ONCE for level 0
__global__ void __launch_bounds__(256) avg_pairs_k(const ushort* __restrict__ h,
    ushort* __restrict__ pre, int P, int offL) {
  long t = (long)blockIdx.x * 256 + threadIdx.x;
  if (t >= (long)2 * P * 128) return;
  int dblk = (int)(t & 127);
  long r = t >> 7;
  int b = (r >= P) ? 1 : 0;
  int p = (int)(r - (long)b * P);
  const ushort* c = h + (((long)(b * H_NODES + offL + 2 * p)) << 10) + dblk * 8;
  const uint4 a0 = *(const uint4*)c;
  const uint4 a1 = *(const uint4*)(c + DIMC);
  const uint32_t* pa = (const uint32_t*)&a0;
  const uint32_t* pb = (const uint32_t*)&a1;
  uint32_t outw[4];
  #pragma unroll
  for (int i = 0; i < 4; ++i) {
    float x0 = b2f((ushort)(pa[i] & 0xffff)), x1 = b2f((ushort)(pa[i] >> 16));
    float y0 = b2f((ushort)(pb[i] & 0xffff)), y1 = b2f((ushort)(pb[i] >> 16));
    ushort r0 = f2b(0.5f * (x0 + y0)), r1 = f2b(0.5f * (x1 + y1));
    outw[i] = (uint32_t)r0 | ((uint32_t)r1 << 16);
  }
  *(uint4*)(pre + (((long)(b * P + p)) << 10) + dblk * 8) = *(const uint4*)outw;
}

// ---------------- GEMM descriptor
struct GemmDesc {
  const ushort* A; long sAb;
  const ushort* Bt;
  const float* bias;
  void* C; long sCb; int ldc;
  int M; int outMode;     // 0 bf16, 1 bf16+bias, 2 fp32+bias
  int tX, tY;
  ushort* preC;           // optional: next-level pre output (avg of row pairs)
  long sPreB;             // batch stride of preC
};

// ---------------- 128x128 pipelined GEMM tile (3-buf, gload_lds) — the ONE gemm core
__device__ __forceinline__ void stage_tile(const GemmDesc& d, const ushort* Ab,
    int row0, int col0, ushort* lA, ushort* lB, int kt, int wave, int lane) {
  #pragma unroll
  for (int j = 0; j < 2; ++j) {
    int s = wave * 128 + j * 64 + lane;
    int r = s >> 2;
    int g = (s & 3) ^ ((r >> 1) & 3);       // pre-swizzled source k-block
    int gr = row0 + r; gr = (gr < d.M) ? gr : (d.M - 1);
    const ushort* srcA = Ab + (long)gr * DIMC + kt * 32 + g * 8;
    __builtin_amdgcn_global_load_lds(
        (const __attribute__((address_space(1))) void*)(uintptr_t)srcA,
        (__attribute__((address_space(3))) void*)(uint32_t)(uintptr_t)(lA + (wave * 128 + j * 64) * 8),
        16, 0, 0);
    const ushort* srcB = d.Bt + (long)(col0 + r) * DIMC + kt * 32 + g * 8;
    __builtin_amdgcn_global_load_lds(
        (const __attribute__((address_space(1))) void*)(uintptr_t)srcB,
        (__attribute__((address_space(3))) void*)(uint32_t)(uintptr_t)(lB + (wave * 128 + j * 64) * 8),
        16, 0, 0);
  }
}

__device__ __forceinline__ void gemm_tile(const GemmDesc& d, int bz, int row0, int col0,
    ushort (*lA)[4096], ushort (*lB)[4096], int tid) {
  const ushort* Ab = d.A + (long)bz * d.sAb;
  int wave = tid >> 6, lane = tid & 63;
  int wr = wave >> 1, wc = wave & 1;

  f32x4 acc[4][4];
  #pragma unroll
  for (int m = 0; m < 4; ++m)
    #pragma unroll
    for (int n = 0; n < 4; ++n) acc[m][n] = (f32x4){0.f, 0.f, 0.f, 0.f};

  stage_tile(d, Ab, row0, col0, lA[0], lB[0], 0, wave, lane);
  stage_tile(d, Ab, row0, col0, lA[1], lB[1], 1, wave, lane);
  asm volatile("s_waitcnt vmcnt(4)" ::: "memory");
  __builtin_amdgcn_s_barrier();

  int rr = lane & 15, g4 = lane >> 4;
  for (int kt = 0; kt < 32; ++kt) {
    int cur = kt % 3;
    if (kt + 2 < 32)
      stage_tile(d, Ab, row0, col0, lA[(kt + 2) % 3], lB[(kt + 2) % 3], kt + 2, wave, lane);
    bf16x8 af[4], bfr[4];
    #pragma unroll
    for (int m = 0; m < 4; ++m) {
      int r = wr * 64 + m * 16 + rr;
      int slot = g4 ^ ((r >> 1) & 3);
      af[m] = *reinterpret_cast<const bf16x8*>(&lA[cur][r * 32 + slot * 8]);
    }
    #pragma unroll
    for (int n = 0; n < 4; ++n) {
      int r = wc * 64 + n * 16 + rr;
      int slot = g4 ^ ((r >> 1) & 3);
      bfr[n] = *reinterpret_cast<const bf16x8*>(&lB[cur][r * 32 + slot * 8]);
    }
    __builtin_amdgcn_s_setprio(1);
    #pragma unroll
    for (int m = 0; m < 4; ++m)
      #pragma unroll
      for (int n = 0; n < 4; ++n)
        acc[m][n] = __builtin_amdgcn_mfma_f32_16x16x32_bf16(af[m], bfr[n], acc[m][n], 0, 0, 0);
    __builtin_amdgcn_s_setprio(0);
    if (kt < 30) { asm volatile("s_waitcnt vmcnt(4)" ::: "memory"); }
    else         { asm volatile("s_waitcnt vmcnt(0)" ::: "memory"); }
    if (kt < 31) __builtin_amdgcn_s_barrier();
  }

  int rq = lane >> 4;
  #pragma unroll
  for (int n = 0; n < 4; ++n) {
    int col = col0 + wc * 64 + n * 16 + rr;
    float bv = d.bias ? d.bias[col] : 0.0f;
    #pragma unroll
    for (int m = 0; m < 4; ++m) {
      int gr0 = row0 + wr * 64 + m * 16 + rq * 4;
      float vv[4];
      #pragma unroll
      for (int r = 0; r < 4; ++r) vv[r] = acc[m][n][r] + bv;
      #pragma unroll
      for (int r = 0; r < 4; ++r) {
        int gr = gr0 + r;
        if (gr < d.M) {
          long o = (long)bz * d.sCb + (long)gr * d.ldc + col;
          if (d.outMode == 2) ((float*)d.C)[o] = vv[r];
          else ((ushort*)d.C)[o] = f2b(vv[r]);
        }
      }
      if (d.preC) {   // fused next-level pre: avg of adjacent row pairs (thread-local)
        #pragma unroll
        for (int r = 0; r < 4; r += 2) {
          int gr = gr0 + r;
          if (gr + 1 < d.M)
            d.preC[(long)bz * d.sPreB + (long)(gr >> 1) * DIMC + col] =
                f2b(0.5f * (vv[r] + vv[r + 1]));
        }
      }
    }
  }
}

// ---------------- the ONE GEMM kernel: two descriptors per launch (proven codegen)
__global__ void __launch_bounds__(256) gemm_multi(GemmDesc d0, GemmDesc d1, int t0) {
  __shared__ __align__(16) ushort lA[3][4096];
  __shared__ __align__(16) ushort lB[3][4096];
  int t = blockIdx.x;
  const GemmDesc& d = (t < t0) ? d0 : d1;
  int u = (t < t0) ? t : t - t0;
  int per = d.tX * d.tY;
  int bz = u / per;
  int rem = u - bz * per;
  int ty = rem / d.tX;
  int tx = rem - ty * d.tX;
  gemm_tile(d, bz, tx * 128, ty * 128, lA, lB, threadIdx.x);
}

// ---------------- stage-1 merge: one wave per (b,p), all 16 heads, 16 elems/lane
__global__ void __launch_bounds__(256) merge_y2_k(const ushort* __restrict__ q,
    const ushort* __restrict__ kv, ushort* __restrict__ outp, int P) {
  int wave = threadIdx.x >> 6, lane = threadIdx.x & 63;
  long w = (long)blockIdx.x * 4 + wave;
  if (w >= (long)2 * P) return;
  int b = (w >= P) ? 1 : 0;
  int p = (int)(w - (long)b * P);
  const ushort* qp = q + (((long)(b * P + p)) << 10) + lane * 16;
  const ushort* kvb = kv + ((long)(b * 2 * P + 2 * p)) * 2048;
  float qf[16], k0f[16], k1f[16];
  load16f(qp, qf);
  load16f(kvb + lane * 16, k0f);
  load16f(kvb + 2048 + lane * 16, k1f);
  float d0 = 0.f, d1 = 0.f;
  #pragma unroll
  for (int j = 0; j < 16; ++j) { d0 += qf[j] * k0f[j]; d1 += qf[j] * k1f[j]; }
  d0 += __shfl_xor(d0, 1); d0 += __shfl_xor(d0, 2);
  d1 += __shfl_xor(d1, 1); d1 += __shfl_xor(d1, 2);
  float s0 = d0 * 0.125f, s1 = d1 * 0.125f;
  float mm = fmaxf(s0, s1);
  float e0 = expf(s0 - mm), e1 = expf(s1 - mm);
  float inv = 1.0f / (e0 + e1 + 1e-9f);
  float w0 = e0 * inv, w1 = e1 * inv;
  float v0f[16], v1f[16], ov[16];
  load16f(kvb + 1024 + lane * 16, v0f);
  load16f(kvb + 2048 + 1024 + lane * 16, v1f);
  #pragma unroll
  for (int j = 0; j < 16; ++j) ov[j] = w0 * v0f[j] + w1 * v1f[j];
  store16b(outp + (((long)(b * P + p)) << 10) + lane * 16, ov);
}

// ---------------- stage-2 gather attention: one wave per (b,n), all heads
__global__ void __launch_bounds__(256) attn_x2_k(const ushort* __restrict__ Q,
    const ushort* __restrict__ KV, ushort* __restrict__ outp) {
  int wave = threadIdx.x >> 6, lane = threadIdx.x & 63;
  long w = (long)blockIdx.x * 4 + wave;
  int n = (int)(w & 4095);
  int b = (int)(w >> 12);
  const ushort* KVb = KV + (long)b * H_NODES * 2048;
  float qf[16];
  load16f(Q + (((long)b * NN + n) << 10) + lane * 16, qf);
  int nb[13];
  nb[0] = n;
  #pragma unroll
  for (int l = 0; l < 12; ++l) nb[1 + l] = (8192 - (8192 >> l)) + ((n >> l) ^ 1);
  float s[13];
  #pragma unroll
  for (int i = 0; i < 13; ++i) {
    float kf[16];
    load16f(KVb + (long)nb[i] * 2048 + lane * 16, kf);
    float d = 0.f;
    #pragma unroll
    for (int j = 0; j < 16; ++j) d += qf[j] * kf[j];
    d += __shfl_xor(d, 1);
    d += __shfl_xor(d, 2);
    s[i] = d * 0.125f;
  }
  #pragma unroll
  for (int l = 0; l < 12; ++l)
    if (((n >> l) & 1) == 0) s[1 + l] = -__builtin_inff();
  float mm = s[0];
  #pragma unroll
  for (int i = 1; i < 13; ++i) mm = fmaxf(mm, s[i]);
  float e[13], sum = 0.f;
  #pragma unroll
  for (int i = 0; i < 13; ++i) { e[i] = expf(s[i] - mm); sum += e[i]; }
  float inv = 1.0f / sum;
  float ov[16];
  #pragma unroll
  for (int j = 0; j < 16; ++j) ov[j] = 0.f;
  #pragma unroll
  for (int i = 0; i < 13; ++i) {
    float wgt = e[i] * inv;
    float vf[16];
    load16f(KVb + (long)nb[i] * 2048 + 1024 + lane * 16, vf);
    #pragma unroll
    for (int j = 0; j < 16; ++j) ov[j] += wgt * vf[j];
  }
  store16b(outp + (((long)b * NN + n) << 10) + lane * 16, ov);
}

extern "C" void kernel_launch(void* const* d_in, const int* in_sizes, int n_in,
                              void* d_out, int out_size, void* d_ws, size_t ws_size,
                              hipStream_t stream) {
  const float* x    = (const float*)d_in[0];
  const float* Wq_y = (const float*)d_in[1];
  const float* Wk_y = (const float*)d_in[2];
  const float* Wv_y = (const float*)d_in[3];
  const float* Wo_y = (const float*)d_in[4];
  const float* bo_y = (const float*)d_in[5];
  const float* Wq_x = (const float*)d_in[6];
  const float* Wk_x = (const float*)d_in[7];
  const float* Wv_x = (const float*)d_in[8];
  const float* Wo_x = (const float*)d_in[9];
  const float* bo_x = (const float*)d_in[10];

  ushort* wt  = (ushort*)d_ws;                              // 8 x 1M bf16 weights^T
  ushort* h   = wt + (size_t)8 * 1024 * 1024;               // [B][8191][1024]
  ushort* reg = h + (size_t)2 * H_NODES * DIMC;
  // stage-2 layout (attached writes begin at level-0 O launch)
  ushort* Qx   = reg;                                       // [B][4096][1024]
  ushort* KVa  = Qx + (size_t)2 * 4096 * DIMC;              // [B][8191][2048]
  ushort* aout = KVa + (size_t)2 * H_NODES * 2048;          // [B][4096][1024]
  // stage-1 scratch lives after aout (aout itself only written by attn, last)
  ushort* preB = aout;                                      // [B][2048][1024]
  ushort* qbB  = preB + (size_t)2 * 2048 * DIMC;            // [B][2048][1024]
  ushort* kv1B = qbB + (size_t)2 * 2048 * DIMC;             // [B][4096][2048]
  ushort* mrgB = kv1B + (size_t)2 * 4096 * 2048;            // [B][2048][1024]
  ushort* preS = preB;
  ushort* qbS  = qbB;
  ushort* kv1S = kv1B;
  ushort* mrgS = mrgB;

  size_t wsElems = (size_t)8 * 1024 * 1024 + (size_t)2 * H_NODES * DIMC +
                   (size_t)2 * 4096 * DIMC + (size_t)2 * H_NODES * 2048 +
                   ((size_t)2 * 2048 * DIMC * 2 + (size_t)2 * 4096 * 2048 +
                    (size_t)2 * 2048 * DIMC);
  if (ws_size < wsElems * 2) return;

  WPtrs wp;
  wp.w[0] = Wq_y; wp.w[1] = Wk_y; wp.w[2] = Wv_y; wp.w[3] = Wo_y;
  wp.w[4] = Wq_x; wp.w[5] = Wk_x; wp.w[6] = Wv_x; wp.w[7] = Wo_x;
  transpose_w_k<<<dim3(32, 32, 8), dim3(32, 8), 0, stream>>>(wp, wt);
  cvt_x_k<<<8192, 256, 0, stream>>>(x, h);
  avg_pairs_k<<<(2 * 2048 * 128 + 255) / 256, 256, 0, stream>>>(h, preB, 2048, 0);

  auto mk128 = [](const ushort* A, long sAb, const ushort* Bt, const float* bias,
                  void* C, long sCb, int ldc, int M, int outMode, int tY) {
    GemmDesc d; d.A = A; d.sAb = sAb; d.Bt = Bt; d.bias = bias; d.C = C; d.sCb = sCb;
    d.ldc = ldc; d.M = M; d.outMode = outMode; d.tX = (M + 127) / 128; d.tY = tY;
    d.preC = nullptr; d.sPreB = 0;
    return d;
  };
  auto kvSub = [&](long start, int len) {
    return mk128(h + start * DIMC, (long)H_NODES * DIMC, wt + (size_t)5 * 1024 * 1024,
                 nullptr, KVa + start * 2048, (long)H_NODES * 2048, 2048, len, 0, 16);
  };
  auto qSub = [&](long start, int len) {
    return mk128(h + start * DIMC, (long)H_NODES * DIMC, wt + (size_t)4 * 1024 * 1024,
                 nullptr, Qx + start * DIMC, (long)4096 * DIMC, DIMC, len, 0, 8);
  };

  for (int l = 0; l < 12; ++l) {
    int P = NN >> (l + 1);
    int offL = 8192 - (8192 >> l);
    int offP = 8192 - (8192 >> (l + 1));
    ushort* pre = (l >= 3) ? preS : preB;
    ushort* qb  = (l >= 3) ? qbS  : qbB;
    ushort* kv1 = (l >= 3) ? kv1S : kv1B;
    ushort* mrg = (l >= 3) ? mrgS : mrgB;

    GemmDesc dq  = mk128(pre, (long)P * DIMC, wt, nullptr,
                         qb, (long)P * DIMC, DIMC, P, 0, 8);
    GemmDesc dkv = mk128(h + (long)offL * DIMC, (long)H_NODES * DIMC,
                         wt + (size_t)1 * 1024 * 1024, nullptr,
                         kv1, (long)2 * P * 2048, 2048, 2 * P, 0, 16);
    int t0 = dq.tX * dq.tY * 2;
    gemm_multi<<<t0 + dkv.tX * dkv.tY * 2, 256, 0, stream>>>(dq, dkv, t0);

    merge_y2_k<<<(2 * P + 3) / 4, 256, 0, stream>>>(qb, kv1, mrg, P);

    GemmDesc dgo = mk128(mrg, (long)P * DIMC, wt + (size_t)3 * 1024 * 1024, bo_y,
                         h + (long)offP * DIMC, (long)H_NODES * DIMC, DIMC, P, 1, 8);
    if (l < 11) {                       // fused pre for next level
      dgo.preC = (l >= 2) ? preS : preB;
      dgo.sPreB = (long)(P / 2) * DIMC;
    }
    // attach schedule (availability: rows < 8192 - (2048>>(l-1)))
    GemmDesc att = dgo; int nAtt = 0;
    if      (l == 0)  att = qSub(0, 2048);
    else if (l == 1)  att = qSub(2048, 2048);
    else if (l == 2)  att = kvSub(0, 1792);
    else if (l == 3)  att = kvSub(1792, 1920);
    else if (l == 4)  att = kvSub(3712, 1920);
    else if (l == 5)  att = kvSub(5632, 1536);
    else if (l == 6)  att = kvSub(7168, 512);
    else if (l == 7)  att = kvSub(7680, 256);
    else if (l == 8)  att = kvSub(7936, 128);
    else if (l == 9)  att = kvSub(8064, 64);
    else if (l == 10) att = kvSub(8128, 32);
    else if (l == 11) att = kvSub(8160, 16);
    nAtt = att.tX * att.tY * 2;
    int n0 = dgo.tX * dgo.tY * 2;
    gemm_multi<<<n0 + nAtt, 256, 0, stream>>>(dgo, att, n0);
  }

  // leftover KV dribble (rows 8176..8190, incl. root; available after l11 O)
  {
    GemmDesc a0 = kvSub(8176, 8), a1 = kvSub(8184, 7);
    int n0 = a0.tX * a0.tY * 2, n1 = a1.tX * a1.tY * 2;
    gemm_multi<<<n0 + n1, 256, 0, stream>>>(a0, a1, n0);
  }
  attn_x2_k<<<2048, 256, 0, stream>>>(Qx, KVa, aout);
  {
    GemmDesc dox = mk128(aout, (long)4096 * DIMC, wt + (size_t)7 * 1024 * 1024, bo_x,
                         d_out, (long)4096 * DIMC, DIMC, 4096, 2, 8);
    gemm_multi<<<dox.tX * dox.tY * 2, 256, 0, stream>>>(dox, dox, dox.tX * dox.tY * 2);
  }
}